// Round 2
// baseline (784.057 us; speedup 1.0000x reference)
//
#include <hip/hip_runtime.h>
#include <math.h>

#define N_NODES 50000
#define N_EDGES 800000
#define E_TOT   (N_EDGES + N_NODES)   // edges + self-loops = 850000
#define F_IN    256
#define NHEAD   8
#define CH      32
#define HC      256                   // NHEAD*CH
#define OUT_C   40
#define NEG_SLOPE 0.2f

// ---------------- GEMM1: h1[N,256] = x[N,256] @ W1[256,256] (fp32)
#define G1_ROWS 32
__global__ __launch_bounds__(256) void gemm1_kernel(const float* __restrict__ x,
        const float* __restrict__ W, float* __restrict__ h1) {
    __shared__ float4 xs[G1_ROWS][F_IN / 4];   // 32 x 64 float4 = 32 KB
    const int row0 = blockIdx.x * G1_ROWS;
    const int tid  = threadIdx.x;
    for (int i = tid; i < G1_ROWS * (F_IN / 4); i += 256) {
        int r  = i >> 6;          // /64
        int k4 = i & 63;
        int gr = row0 + r;
        float4 v = make_float4(0.f, 0.f, 0.f, 0.f);
        if (gr < N_NODES) v = ((const float4*)(x + (size_t)gr * F_IN))[k4];
        xs[r][k4] = v;
    }
    __syncthreads();
    const int c = tid;  // output column 0..255
    float acc[G1_ROWS];
    #pragma unroll
    for (int r = 0; r < G1_ROWS; ++r) acc[r] = 0.f;
    for (int k0 = 0; k0 < F_IN; k0 += 4) {
        float w0 = W[(k0 + 0) * HC + c];
        float w1 = W[(k0 + 1) * HC + c];
        float w2 = W[(k0 + 2) * HC + c];
        float w3 = W[(k0 + 3) * HC + c];
        #pragma unroll
        for (int r = 0; r < G1_ROWS; ++r) {
            float4 xv = xs[r][k0 >> 2];   // same addr for all lanes -> LDS broadcast
            acc[r] += xv.x * w0 + xv.y * w1 + xv.z * w2 + xv.w * w3;
        }
    }
    #pragma unroll
    for (int r = 0; r < G1_ROWS; ++r) {
        int gr = row0 + r;
        if (gr < N_NODES) h1[(size_t)gr * HC + c] = acc[r];
    }
}

// ---------------- GEMM2: h2[N,256] = hmid[N,32] @ W2[32,256]
__global__ __launch_bounds__(256) void gemm2_kernel(const float* __restrict__ hm,
        const float* __restrict__ W, float* __restrict__ h2) {
    const int n = blockIdx.x;
    const int c = threadIdx.x;
    __shared__ float hrow[CH];
    if (threadIdx.x < CH) hrow[threadIdx.x] = hm[n * CH + threadIdx.x];
    __syncthreads();
    float acc = 0.f;
    #pragma unroll
    for (int k = 0; k < CH; ++k) acc += hrow[k] * W[k * HC + c];
    h2[(size_t)n * HC + c] = acc;
}

// ---------------- per-node attention coefficients: asrc/adst [N,8]
__global__ __launch_bounds__(256) void alpha_kernel(const float* __restrict__ h,
        const float* __restrict__ a_src, const float* __restrict__ a_dst,
        float* __restrict__ asrc, float* __restrict__ adst) {
    int t = blockIdx.x * 256 + threadIdx.x;
    if (t >= N_NODES * NHEAD) return;
    int node = t >> 3;
    int hd   = t & 7;
    const float4* hp = (const float4*)(h + (size_t)node * HC + hd * CH);
    const float4* ap = (const float4*)(a_src + hd * CH);
    const float4* dp = (const float4*)(a_dst + hd * CH);
    float s1 = 0.f, s2 = 0.f;
    #pragma unroll
    for (int i = 0; i < CH / 4; ++i) {
        float4 hv = hp[i], av = ap[i], dv = dp[i];
        s1 += hv.x * av.x + hv.y * av.y + hv.z * av.z + hv.w * av.w;
        s2 += hv.x * dv.x + hv.y * dv.y + hv.z * dv.z + hv.w * dv.w;
    }
    asrc[t] = s1;
    adst[t] = s2;
}

// ---------------- pass 1: per-(edge,head) exp(e); accumulate softmax denoms
// (no max-subtraction: e is O(1) by construction, softmax is shift-invariant)
__global__ __launch_bounds__(256) void edge_exp_kernel(const int* __restrict__ ei,
        const float* __restrict__ asrc, const float* __restrict__ adst,
        float* __restrict__ ew, float* __restrict__ s) {
    int t = blockIdx.x * 256 + threadIdx.x;
    if (t >= E_TOT * NHEAD) return;
    int j  = t >> 3;
    int hd = t & 7;
    int src, dst;
    if (j < N_EDGES) { src = ei[j]; dst = ei[N_EDGES + j]; }
    else             { src = j - N_EDGES; dst = src; }
    float e = asrc[src * NHEAD + hd] + adst[dst * NHEAD + hd];
    e = e > 0.f ? e : NEG_SLOPE * e;
    float ex = __expf(e);
    ew[t] = ex;
    atomicAdd(&s[dst * NHEAD + hd], ex);
}

// s -> 1/(8*s)  (folds the head-mean)
__global__ __launch_bounds__(256) void sinv_kernel(const float* __restrict__ s,
        float* __restrict__ sinv) {
    int t = blockIdx.x * 256 + threadIdx.x;
    if (t >= N_NODES * NHEAD) return;
    sinv[t] = 1.0f / (8.0f * s[t]);
}

// ---------------- pass 1b: fold denominators into edge weights (in place)
__global__ __launch_bounds__(256) void edge_w_kernel(const int* __restrict__ ei,
        const float* __restrict__ sinv, float* __restrict__ ew) {
    int t = blockIdx.x * 256 + threadIdx.x;
    if (t >= E_TOT * NHEAD) return;
    int j  = t >> 3;
    int hd = t & 7;
    int dst;
    if (j < N_EDGES) dst = ei[N_EDGES + j];
    else             dst = j - N_EDGES;
    ew[t] *= sinv[dst * NHEAD + hd];
}

// ---------------- pass 2: aggregation, one thread per (edge, channel)
__global__ __launch_bounds__(256) void aggregate_kernel(const int* __restrict__ ei,
        const float* __restrict__ ew, const float* __restrict__ h,
        float* __restrict__ outacc) {
    int gid = blockIdx.x * 256 + threadIdx.x;
    int j = gid >> 5;
    int c = gid & 31;
    if (j >= E_TOT) return;
    int src, dst;
    if (j < N_EDGES) { src = ei[j]; dst = ei[N_EDGES + j]; }
    else             { src = j - N_EDGES; dst = src; }
    const float* wp = ew + (size_t)j * NHEAD;        // broadcast across 32 lanes
    const float* hp = h + (size_t)src * HC + c;      // stride-32 per head
    float val = 0.f;
    #pragma unroll
    for (int hd = 0; hd < NHEAD; ++hd) val += wp[hd] * hp[hd * CH];
    atomicAdd(&outacc[dst * CH + c], val);
}

// ---------------- finalize a GAT layer: +bias, ELU (in place, fp32)
__global__ __launch_bounds__(256) void finalize_kernel(float* __restrict__ acc,
        const float* __restrict__ b) {
    int t = blockIdx.x * 256 + threadIdx.x;
    if (t >= N_NODES * CH) return;
    int c = t & (CH - 1);
    float v = acc[t] + b[c];
    acc[t] = v > 0.f ? v : (__expf(v) - 1.f);
}

// ---------------- output head: logits = h@Wo + bo, log_softmax (1 wave/node)
__global__ __launch_bounds__(64) void out_kernel(const float* __restrict__ hf,
        const float* __restrict__ Wo, const float* __restrict__ bo,
        float* __restrict__ out) {
    const int n = blockIdx.x;
    const int lane = threadIdx.x;
    __shared__ float hs[CH];
    if (lane < CH) hs[lane] = hf[n * CH + lane];
    __syncthreads();
    float logit = -INFINITY;
    if (lane < OUT_C) {
        float a = bo[lane];
        #pragma unroll
        for (int k = 0; k < CH; ++k) a += hs[k] * Wo[k * OUT_C + lane];
        logit = a;
    }
    float m = logit;
    #pragma unroll
    for (int off = 32; off; off >>= 1) m = fmaxf(m, __shfl_xor(m, off, 64));
    float ex = (lane < OUT_C) ? __expf(logit - m) : 0.f;
    float ssum = ex;
    #pragma unroll
    for (int off = 32; off; off >>= 1) ssum += __shfl_xor(ssum, off, 64);
    if (lane < OUT_C) out[(size_t)n * OUT_C + lane] = logit - m - __logf(ssum);
}

extern "C" void kernel_launch(void* const* d_in, const int* in_sizes, int n_in,
                              void* d_out, int out_size, void* d_ws, size_t ws_size,
                              hipStream_t stream) {
    const float* x      = (const float*)d_in[0];
    const int*   ei     = (const int*)  d_in[1];
    const float* W1     = (const float*)d_in[2];
    const float* a_src1 = (const float*)d_in[3];
    const float* a_dst1 = (const float*)d_in[4];
    const float* b1     = (const float*)d_in[5];
    const float* W2     = (const float*)d_in[6];
    const float* a_src2 = (const float*)d_in[7];
    const float* a_dst2 = (const float*)d_in[8];
    const float* b2     = (const float*)d_in[9];
    const float* Wo     = (const float*)d_in[10];
    const float* bo     = (const float*)d_in[11];
    float* out = (float*)d_out;

    // workspace carve-up (256B-aligned)
    char* ws = (char*)d_ws;
    size_t off = 0;
    auto carve = [&](size_t bytes) { char* p = ws + off; off += (bytes + 255) & ~(size_t)255; return p; };
    float* h_big = (float*)carve((size_t)N_NODES * HC * 4);     // 51.2 MB (h1, then h2)
    float* asrc  = (float*)carve((size_t)N_NODES * NHEAD * 4);  // 1.6 MB
    float* adst  = (float*)carve((size_t)N_NODES * NHEAD * 4);
    float* s     = (float*)carve((size_t)N_NODES * NHEAD * 4);
    float* sinv  = (float*)carve((size_t)N_NODES * NHEAD * 4);
    float* ew    = (float*)carve((size_t)E_TOT * NHEAD * 4);    // 27.2 MB
    float* acc1  = (float*)carve((size_t)N_NODES * CH * 4);     // 6.4 MB (-> hmid in place)
    float* acc2  = (float*)carve((size_t)N_NODES * CH * 4);     // 6.4 MB (-> hout in place)

    const int g_gemm1 = (N_NODES + G1_ROWS - 1) / G1_ROWS;        // 1563
    const int g_nh    = (N_NODES * NHEAD + 255) / 256;            // 1563
    const int g_eh    = (E_TOT * NHEAD + 255) / 256;              // 26563
    const int g_aggr  = (E_TOT * 32 + 255) / 256;                 // 106250
    const int g_fin   = (N_NODES * CH + 255) / 256;               // 6250

    // ---------- layer 1 ----------
    hipMemsetAsync(s, 0, (size_t)N_NODES * NHEAD * 4, stream);
    hipMemsetAsync(acc1, 0, (size_t)N_NODES * CH * 4, stream);
    gemm1_kernel<<<g_gemm1, 256, 0, stream>>>(x, W1, h_big);
    alpha_kernel<<<g_nh, 256, 0, stream>>>(h_big, a_src1, a_dst1, asrc, adst);
    edge_exp_kernel<<<g_eh, 256, 0, stream>>>(ei, asrc, adst, ew, s);
    sinv_kernel<<<g_nh, 256, 0, stream>>>(s, sinv);
    edge_w_kernel<<<g_eh, 256, 0, stream>>>(ei, sinv, ew);
    aggregate_kernel<<<g_aggr, 256, 0, stream>>>(ei, ew, h_big, acc1);
    finalize_kernel<<<g_fin, 256, 0, stream>>>(acc1, b1);

    // ---------- layer 2 ----------
    hipMemsetAsync(s, 0, (size_t)N_NODES * NHEAD * 4, stream);
    hipMemsetAsync(acc2, 0, (size_t)N_NODES * CH * 4, stream);
    gemm2_kernel<<<N_NODES, 256, 0, stream>>>(acc1, W2, h_big);
    alpha_kernel<<<g_nh, 256, 0, stream>>>(h_big, a_src2, a_dst2, asrc, adst);
    edge_exp_kernel<<<g_eh, 256, 0, stream>>>(ei, asrc, adst, ew, s);
    sinv_kernel<<<g_nh, 256, 0, stream>>>(s, sinv);
    edge_w_kernel<<<g_eh, 256, 0, stream>>>(ei, sinv, ew);
    aggregate_kernel<<<g_aggr, 256, 0, stream>>>(ei, ew, h_big, acc2);
    finalize_kernel<<<g_fin, 256, 0, stream>>>(acc2, b2);

    // ---------- output head ----------
    out_kernel<<<N_NODES, 64, 0, stream>>>(acc2, Wo, bo, out);
}